// Round 6
// baseline (94.132 us; speedup 1.0000x reference)
//
#include <hip/hip_runtime.h>
#include <hip/hip_bf16.h>
#include <cstddef>

// ---------------- problem dims (hard-coded from reference) ----------------
constexpr int cB=4, cN=2000, cT=50, cF=10, cD=64, cR=8, cK=16, cE=32;
constexpr int NODES = cB*cN;     // 8000
constexpr int N1    = cN+1;      // 2001 (padded table incl. zero row m=0)
constexpr int ROWS2 = cB*N1;     // 8004

#define DEV static __device__ __forceinline__

typedef __attribute__((ext_vector_type(8))) short bf16x8;   // 8 bf16 = 4 VGPR
typedef __attribute__((ext_vector_type(4))) float f32x4;
typedef __attribute__((ext_vector_type(4))) int   i32x4;

DEV float leaky(float x){ return fmaxf(x, 0.2f*x); }
DEV float wsumall(float v){           // butterfly all-reduce over 64 lanes
  v += __shfl_xor(v,32,64); v += __shfl_xor(v,16,64); v += __shfl_xor(v,8,64);
  v += __shfl_xor(v,4,64);  v += __shfl_xor(v,2,64);  v += __shfl_xor(v,1,64);
  return v;
}
DEV unsigned fu(float f){ return __float_as_uint(f); }
DEV float hif(float f){ return __uint_as_float(fu(f) & 0xFFFF0000u); }   // truncate to bf16-in-f32
DEV unsigned rne16(float f){                                             // RNE bf16 bits of f
  unsigned u = fu(f);
  return (u + 0x7FFFu + ((u>>16)&1u)) >> 16;
}
DEV bf16x8 pack4(unsigned a, unsigned b, unsigned c2, unsigned d){
  union { i32x4 i; bf16x8 h; } u;
  u.i = (i32x4){(int)a,(int)b,(int)c2,(int)d};
  return u.h;
}
DEV unsigned PLO(unsigned x, unsigned y){ return __builtin_amdgcn_perm(y, x, 0x05040100u); }
DEV unsigned PHI(unsigned x, unsigned y){ return __builtin_amdgcn_perm(y, x, 0x07060302u); }
// (hi-trunc of f | hi-trunc of rem<<16) in 3 ops: and, sub, perm
DEV unsigned pack_hl3(float f){
  float rem = f - hif(f);
  return PHI(fu(f), fu(rem));
}
DEV f32x4 MF(bf16x8 a, bf16x8 b, f32x4 c){
  return __builtin_amdgcn_mfma_f32_16x16x32_bf16(a, b, c, 0, 0, 0);
}
DEV float bfu(unsigned short u){ return __uint_as_float(((unsigned)u)<<16); }
DEV float ex2(float x){ float r; asm("v_exp_f32 %0, %1" : "=v"(r) : "v"(x)); return r; }

// ========== K1: GRU (MFMA, K-split 8-wave) + fused projection ============
// Block = 512 thr = 8 waves over 16 nodes. Owner wave w<4 owns gate d-slice
// [16w,16w+16) and the K=0..31 half (12 MFMA) + gate math; partner wave w+4
// computes the K=32..63 half (9 MFMA) and exchanges 3 partial C-tiles via
// LDS (same lane->(m,n) mapping, so combine = 3 b128 reads + vector adds).
// 4000 waves -> 4/SIMD. log2e/sign folded into U/W/b: sigmoid/tanh use
// native v_exp_f32 (exp2) directly. Two lgkm-only barriers per step; X
// prefetch (2 ahead, owner-only) never drained. Epilogue: wave w8 projects
// the block's 16 nodes for relation r=w8 (16 MFMA) -> actb bf16 + sng2.
__global__ __launch_bounds__(512, 4) void k_gru(const float* __restrict__ X,
    const float* __restrict__ gW, const float* __restrict__ gU,
    const float* __restrict__ gb, const float* __restrict__ pW,
    const float* __restrict__ pb, const float* __restrict__ sattW,
    float* __restrict__ node, unsigned short* __restrict__ actb,
    float* __restrict__ sng2)
{
  __shared__ unsigned sH[2][1024];                 // [buf][node*64+d] ^ ((node&7)<<2)
  __shared__ __align__(16) float pP[4][3][256];    // partner partials, C-layout c*16+kg*4

  const int tid  = threadIdx.x;
  const int lane = tid & 63;
  const int w8   = tid >> 6;            // 0..7
  const int w    = w8 & 3;              // d-slice
  const bool owner = (w8 < 4);
  const int s    = owner ? 0 : 1;       // K-half this wave handles
  const int c    = lane & 15;
  const int kg   = lane >> 4;
  const int nb   = (int)blockIdx.x * 16;
  const int col  = 16*w + c;
  const int bb   = nb / cN;             // batch (block-uniform)

  const float SZ = -1.4426950408889634f;   // -log2(e): z,r gates
  const float SH =  2.8853900817779268f;   // 2*log2(e): h~ gate

  // ---- B fragments for this wave's K-half (scaled U, split hi/lo RNE) ----
  const float scl0 = SZ, scl1 = SZ, scl2 = SH;
  bf16x8 Uhi[3], Ulo[3], BXv[3];
  #pragma unroll
  for (int cls=0; cls<3; ++cls){
    const float sc = (cls==2) ? scl2 : (cls==1 ? scl1 : scl0);
    const int n = cls*64 + col;
    unsigned hi[4], lo[4];
    #pragma unroll
    for (int p=0;p<4;++p){
      float u0 = sc * gU[(s*32 + kg*8 + 2*p    )*192 + n];
      float u1 = sc * gU[(s*32 + kg*8 + 2*p + 1)*192 + n];
      hi[p] = (fu(u0)>>16) | (fu(u1) & 0xFFFF0000u);
      lo[p] = rne16(u0 - hif(u0)) | (rne16(u1 - hif(u1)) << 16);
    }
    Uhi[cls] = pack4(hi[0],hi[1],hi[2],hi[3]);
    Ulo[cls] = pack4(lo[0],lo[1],lo[2],lo[3]);
  }
  #pragma unroll
  for (int cls=0; cls<3; ++cls){
    const float sc = (cls==2) ? scl2 : scl0;
    const int n = cls*64 + col;
    unsigned wd[4];
    #pragma unroll
    for (int p=0;p<4;++p){
      int f = kg*4 + p;
      unsigned v = (f < cF) ? rne16(sc * gW[f*192 + n]) : 0u;
      wd[p] = v | (v << 16);            // k=2f (x_hi) and k=2f+1 (x_lo)
    }
    BXv[cls] = pack4(wd[0],wd[1],wd[2],wd[3]);
  }

  // ---- scaled biases -> accumulator inits (owner uses) ----
  const float bz  = SZ*(gb[col]      + gb[192+col]);
  const float br  = SZ*(gb[64+col]   + gb[256+col]);
  const float bh0 = SH* gb[128+col];
  const float bh1 = SH* gb[320+col];

  // ---- zero h-tile buffer 0 ----
  for (int i2 = tid; i2 < 1024; i2 += 512) sH[0][i2] = 0u;
  f32x4 ho = {0.f,0.f,0.f,0.f};
  __syncthreads();

  // ---- x prefetch, 2 steps ahead (owner waves use) ----
  float xc[4], xn[4];
  const float* Xb = X + (size_t)(nb + c)*cT*cF;
  {
    #pragma unroll
    for (int p=0;p<4;++p){ int f = 4*kg+p; xc[p] = (f < cF) ? Xb[0*cF + f] : 0.f; }
    #pragma unroll
    for (int p=0;p<4;++p){ int f = 4*kg+p; xn[p] = (f < cF) ? Xb[1*cF + f] : 0.f; }
  }

  const unsigned sw  = (unsigned)((c&7)<<2);
  const unsigned rb0 = (unsigned)(c*64 + kg*8);
  float* pw0 = &pP[w][0][c*16 + kg*4];
  float* pw1 = &pP[w][1][c*16 + kg*4];
  float* pw2 = &pP[w][2][c*16 + kg*4];

  for (int t = 0; t < cT; ++t){
    const unsigned* sr = sH[t & 1];
    f32x4 aZ, aR, aHc, aXh;
    if (owner){
      // ---- x A-fragment: dword p = (hi|lo-trunc) of x[f=4kg+p] ----
      bf16x8 xf = pack4(pack_hl3(xc[0]), pack_hl3(xc[1]),
                        pack_hl3(xc[2]), pack_hl3(xc[3]));
      #pragma unroll
      for (int p=0;p<4;++p) xc[p] = xn[p];
      {
        int tn = (t+2 < cT) ? t+2 : cT-1;
        #pragma unroll
        for (int p=0;p<4;++p){ int f = 4*kg+p; xn[p] = (f < cF) ? Xb[(size_t)tn*cF + f] : 0.f; }
      }
      // ---- h A-fragments, K=0..31 ----
      i32x4 qa = *(const i32x4*)(sr + ((rb0 +  0) ^ sw));
      i32x4 qb = *(const i32x4*)(sr + ((rb0 +  4) ^ sw));
      bf16x8 hh0 = pack4(PLO(qa[0],qa[1]), PLO(qa[2],qa[3]), PLO(qb[0],qb[1]), PLO(qb[2],qb[3]));
      bf16x8 hl0 = pack4(PHI(qa[0],qa[1]), PHI(qa[2],qa[3]), PHI(qb[0],qb[1]), PHI(qb[2],qb[3]));
      aZ  = (f32x4){bz,bz,bz,bz};
      aR  = (f32x4){br,br,br,br};
      aHc = (f32x4){bh1,bh1,bh1,bh1};
      aXh = (f32x4){bh0,bh0,bh0,bh0};
      aZ  = MF(xf, BXv[0], aZ);
      aR  = MF(xf, BXv[1], aR);
      aXh = MF(xf, BXv[2], aXh);
      aZ  = MF(hh0, Uhi[0], aZ);
      aR  = MF(hh0, Uhi[1], aR);
      aHc = MF(hh0, Uhi[2], aHc);
      aZ  = MF(hl0, Uhi[0], aZ);
      aR  = MF(hl0, Uhi[1], aR);
      aHc = MF(hl0, Uhi[2], aHc);
      aZ  = MF(hh0, Ulo[0], aZ);
      aR  = MF(hh0, Ulo[1], aR);
      aHc = MF(hh0, Ulo[2], aHc);
    } else {
      // ---- h A-fragments, K=32..63 ----
      i32x4 qc = *(const i32x4*)(sr + ((rb0 + 32) ^ sw));
      i32x4 qd = *(const i32x4*)(sr + ((rb0 + 36) ^ sw));
      bf16x8 hh1 = pack4(PLO(qc[0],qc[1]), PLO(qc[2],qc[3]), PLO(qd[0],qd[1]), PLO(qd[2],qd[3]));
      bf16x8 hl1 = pack4(PHI(qc[0],qc[1]), PHI(qc[2],qc[3]), PHI(qd[0],qd[1]), PHI(qd[2],qd[3]));
      f32x4 pz = {0.f,0.f,0.f,0.f}, pr = {0.f,0.f,0.f,0.f}, ph = {0.f,0.f,0.f,0.f};
      pz = MF(hh1, Uhi[0], pz);
      pr = MF(hh1, Uhi[1], pr);
      ph = MF(hh1, Uhi[2], ph);
      pz = MF(hl1, Uhi[0], pz);
      pr = MF(hl1, Uhi[1], pr);
      ph = MF(hl1, Uhi[2], ph);
      pz = MF(hh1, Ulo[0], pz);
      pr = MF(hh1, Ulo[1], pr);
      ph = MF(hh1, Ulo[2], ph);
      *(f32x4*)pw0 = pz;
      *(f32x4*)pw1 = pr;
      *(f32x4*)pw2 = ph;
    }
    asm volatile("s_waitcnt lgkmcnt(0)" ::: "memory");
    __builtin_amdgcn_s_barrier();

    if (owner){
      f32x4 p0 = *(const f32x4*)pw0;
      f32x4 p1 = *(const f32x4*)pw1;
      f32x4 p2 = *(const f32x4*)pw2;
      aZ  = aZ  + p0;
      aR  = aR  + p1;
      aHc = aHc + p2;
      unsigned* swr = sH[(t & 1) ^ 1];
      #pragma unroll
      for (int reg=0; reg<4; ++reg){
        float z   = __builtin_amdgcn_rcpf(1.0f + ex2(aZ[reg]));
        float r   = __builtin_amdgcn_rcpf(1.0f + ex2(aR[reg]));
        float phv = __builtin_fmaf(r, aHc[reg], aXh[reg]);
        float th  = __builtin_fmaf(-2.0f, __builtin_amdgcn_rcpf(ex2(phv) + 1.0f), 1.0f);
        float hn  = __builtin_fmaf(z, ho[reg]-th, th);
        ho[reg] = hn;
        int nodei = kg*4 + reg;
        swr[((unsigned)(nodei*64 + col)) ^ ((unsigned)((nodei&7)<<2))] = pack_hl3(hn);
      }
    }
    asm volatile("s_waitcnt lgkmcnt(0)" ::: "memory");
    __builtin_amdgcn_s_barrier();
  }

  // ---- write out h (fp32) for k_attn (owner waves hold ho) ----
  if (owner){
    #pragma unroll
    for (int reg=0; reg<4; ++reg)
      node[(size_t)(nb + kg*4 + reg)*cD + col] = ho[reg];
  }

  // ================= fused projection epilogue: r = w8 =================
  // final h (hi|lo) is in sH[0] (t=49 wrote buf 0; barrier passed)
  {
    const unsigned* sr = &sH[0][0];
    i32x4 qa = *(const i32x4*)(sr + ((rb0 +  0) ^ sw));
    i32x4 qb = *(const i32x4*)(sr + ((rb0 +  4) ^ sw));
    i32x4 qc = *(const i32x4*)(sr + ((rb0 + 32) ^ sw));
    i32x4 qd = *(const i32x4*)(sr + ((rb0 + 36) ^ sw));
    bf16x8 hh0 = pack4(PLO(qa[0],qa[1]), PLO(qa[2],qa[3]), PLO(qb[0],qb[1]), PLO(qb[2],qb[3]));
    bf16x8 hl0 = pack4(PHI(qa[0],qa[1]), PHI(qa[2],qa[3]), PHI(qb[0],qb[1]), PHI(qb[2],qb[3]));
    bf16x8 hh1 = pack4(PLO(qc[0],qc[1]), PLO(qc[2],qc[3]), PLO(qd[0],qd[1]), PLO(qd[2],qd[3]));
    bf16x8 hl1 = pack4(PHI(qc[0],qc[1]), PHI(qc[2],qc[3]), PHI(qd[0],qd[1]), PHI(qd[2],qd[3]));

    const int qbase = nb + bb + 1;        // padded-table row of node nb
    const int r = w8;
    const float* Pr = pW + (size_t)r*cD*cD;
    bf16x8 PB[4][2];
    float pbv[4], wnv[4];
    #pragma unroll
    for (int cb=0; cb<4; ++cb){
      const int e = 16*cb + c;
      #pragma unroll
      for (int s2=0;s2<2;++s2){
        unsigned wd[4];
        #pragma unroll
        for (int p=0;p<4;++p){
          int k0 = s2*32 + kg*8 + 2*p;
          wd[p] = rne16(Pr[(size_t)k0*cD + e]) | (rne16(Pr[(size_t)(k0+1)*cD + e]) << 16);
        }
        PB[cb][s2] = pack4(wd[0],wd[1],wd[2],wd[3]);
      }
      pbv[cb] = pb[r*cD + e];
      wnv[cb] = sattW[r*(2*cD+cE) + cD + e];
    }
    float sp[4] = {0.f,0.f,0.f,0.f};
    #pragma unroll
    for (int cb=0; cb<4; ++cb){
      f32x4 acc = {pbv[cb],pbv[cb],pbv[cb],pbv[cb]};
      acc = MF(hh0, PB[cb][0], acc); acc = MF(hh1, PB[cb][1], acc);
      acc = MF(hl0, PB[cb][0], acc); acc = MF(hl1, PB[cb][1], acc);
      #pragma unroll
      for (int reg=0; reg<4; ++reg){
        float o = leaky(acc[reg]);
        int qrow = qbase + kg*4 + reg;
        actb[((size_t)r*ROWS2 + qrow)*cD + 16*cb + c] = (unsigned short)rne16(o);
        sp[reg] = __builtin_fmaf(o, wnv[cb], sp[reg]);
      }
    }
    #pragma unroll
    for (int reg=0; reg<4; ++reg){
      float s2 = sp[reg];
      s2 += __shfl_xor(s2,1,64); s2 += __shfl_xor(s2,2,64);
      s2 += __shfl_xor(s2,4,64); s2 += __shfl_xor(s2,8,64);
      if (c == 0) sng2[(size_t)r*ROWS2 + qbase + kg*4 + reg] = s2;
    }
  }

  // ---- 4 designated blocks write the m=0 (zero-input) rows ----
  if ((blockIdx.x % (cN/16)) == 0){
    const int r = w8;
    float v0 = leaky(pb[r*cD + lane]);
    float wv = sattW[r*(2*cD+cE) + cD + lane];
    actb[((size_t)r*ROWS2 + (size_t)bb*N1)*cD + lane] = (unsigned short)rne16(v0);
    float s2 = wsumall(v0 * wv);
    if (lane == 0) sng2[(size_t)r*ROWS2 + (size_t)bb*N1] = s2;
  }
}

// ============ K3: fused attention + head (+ per-r scalars), 1 wave/(b,n) ==
__global__ __launch_bounds__(256) void k_attn(const float* __restrict__ node,
    const int* __restrict__ nbrs, const float* __restrict__ sattW,
    const float* __restrict__ sattb, const float* __restrict__ rattW,
    const float* __restrict__ rattb, const float* __restrict__ predW,
    const float* __restrict__ predb, const float* __restrict__ relemb,
    const unsigned short* __restrict__ actb, const float* __restrict__ sng2,
    float* __restrict__ out)
{
  __shared__ float sSA[cR][cD];        // w_cur rows
  __shared__ float sSrel[cR], sRremb[cR];
  __shared__ float sAtt[4][cR][cK];
  __shared__ int   sOff[4][cR][cK];
  const int tid = threadIdx.x;
  for (int i=tid; i<cR*cD; i+=256) sSA[i>>6][i&63] = sattW[(i>>6)*(2*cD+cE) + (i&63)];
  if (tid < 64){                       // fold old k_prep: srel, rremb
    int r = tid >> 3, j0 = (tid & 7)*4;
    float a = 0.f, b2 = 0.f;
    #pragma unroll
    for (int j=0;j<4;++j){
      float re = relemb[r*cE + j0 + j];
      a  += re * sattW[r*(2*cD+cE) + 2*cD + j0 + j];
      b2 += re * rattW[2*cD + j0 + j];
    }
    a  += __shfl_xor(a,1,64);  a  += __shfl_xor(a,2,64);  a  += __shfl_xor(a,4,64);
    b2 += __shfl_xor(b2,1,64); b2 += __shfl_xor(b2,2,64); b2 += __shfl_xor(b2,4,64);
    if ((tid & 7) == 0){ sSrel[r] = a + sattb[r]; sRremb[r] = b2; }
  }
  __syncthreads();

  const int wave = tid >> 6, lane = tid & 63;
  const int gn = (int)blockIdx.x*4 + wave;          // 0..7999
  const int b = __builtin_amdgcn_readfirstlane(gn / cN);
  const int n = __builtin_amdgcn_readfirstlane(gn % cN);

  const float cur = node[(size_t)gn*cD + lane];

  float scr[8];
  #pragma unroll
  for (int r=0; r<8; ++r) scr[r] = wsumall(cur * sSA[r][lane]);

  const int g = lane >> 4, k = lane & 15;
  #pragma unroll
  for (int half=0; half<2; ++half){
    int r = half*4 + g;
    float sc0 = half==0 ? (g==0?scr[0]:g==1?scr[1]:g==2?scr[2]:scr[3])
                        : (g==0?scr[4]:g==1?scr[5]:g==2?scr[6]:scr[7]);
    int idx = nbrs[(((size_t)b*cR + r)*cN + n)*cK + k];
    int o = r*ROWS2 + b*N1 + idx;
    float sv = sng2[o];
    float sc = leaky(sc0 + sv + sSrel[r]);
    if (idx == 0) sc -= 1e9f;
    float mx = sc;
    mx = fmaxf(mx, __shfl_xor(mx,1,64)); mx = fmaxf(mx, __shfl_xor(mx,2,64));
    mx = fmaxf(mx, __shfl_xor(mx,4,64)); mx = fmaxf(mx, __shfl_xor(mx,8,64));
    float ex = __expf(sc - mx);
    float sm = ex;
    sm += __shfl_xor(sm,1,64); sm += __shfl_xor(sm,2,64);
    sm += __shfl_xor(sm,4,64); sm += __shfl_xor(sm,8,64);
    sAtt[wave][r][k] = ex/sm;
    sOff[wave][r][k] = o;
  }
  __syncthreads();

  float facc[8];
  #pragma unroll
  for (int r=0; r<8; ++r){
    float a0=0.f, a1=0.f;
    #pragma unroll
    for (int kk=0; kk<cK; kk+=2){
      float w0 = sAtt[wave][r][kk],   w1 = sAtt[wave][r][kk+1];
      int   o0 = sOff[wave][r][kk],   o1 = sOff[wave][r][kk+1];
      a0 += w0 * bfu(actb[(size_t)o0*cD + lane]);
      a1 += w1 * bfu(actb[(size_t)o1*cD + lane]);
    }
    facc[r] = a0 + a1;
  }

  const float rcur = rattW[lane], rrep = rattW[cD + lane];
  const float rb   = rattb[0];
  const float c0 = wsumall(cur * rcur);
  float rs[8];
  #pragma unroll
  for (int r=0; r<8; ++r) rs[r] = leaky(c0 + wsumall(facc[r]*rrep) + sRremb[r] + rb);
  float mx = rs[0];
  #pragma unroll
  for (int r=1; r<8; ++r) mx = fmaxf(mx, rs[r]);
  float es = 0.f; float ratt[8];
  #pragma unroll
  for (int r=0; r<8; ++r){ ratt[r] = __expf(rs[r]-mx); es += ratt[r]; }
  float inv = 1.f/es;
  float agg = 0.f;
  #pragma unroll
  for (int r=0; r<8; ++r) agg += (ratt[r]*inv) * facc[r];
  const float upd = cur + agg;

  float l0 = wsumall(upd * predW[lane*3 + 0]);
  float l1 = wsumall(upd * predW[lane*3 + 1]);
  float l2 = wsumall(upd * predW[lane*3 + 2]);
  if (lane == 0){
    l0 += predb[0]; l1 += predb[1]; l2 += predb[2];
    float m2 = fmaxf(l0, fmaxf(l1, l2));
    float e0 = __expf(l0-m2), e1 = __expf(l1-m2), e2 = __expf(l2-m2);
    float is = 1.f/(e0+e1+e2);
    out[(size_t)gn*3+0] = e0*is;
    out[(size_t)gn*3+1] = e1*is;
    out[(size_t)gn*3+2] = e2*is;
  }
}

// ================================ launch =================================
extern "C" void kernel_launch(void* const* d_in, const int* in_sizes, int n_in,
                              void* d_out, int out_size, void* d_ws, size_t ws_size,
                              hipStream_t stream)
{
  const float* X      = (const float*)d_in[0];
  const int*   nbrs   = (const int*)  d_in[1];
  const float* gW     = (const float*)d_in[2];
  const float* gU     = (const float*)d_in[3];
  const float* gb     = (const float*)d_in[4];
  const float* relemb = (const float*)d_in[5];
  const float* pW     = (const float*)d_in[6];
  const float* pb     = (const float*)d_in[7];
  const float* sattW  = (const float*)d_in[8];
  const float* sattb  = (const float*)d_in[9];
  const float* rattW  = (const float*)d_in[10];
  const float* rattb  = (const float*)d_in[11];
  const float* predW  = (const float*)d_in[12];
  const float* predb  = (const float*)d_in[13];
  float* out = (float*)d_out;

  // workspace: node fp32 | act bf16 (r-major) | sng fp32
  float*          node  = (float*)d_ws;                                 // NODES*cD
  unsigned short* actb  = (unsigned short*)(node + (size_t)NODES*cD);   // cR*ROWS2*cD bf16
  float*          sng2  = (float*)(actb + (size_t)cR*ROWS2*cD);         // cR*ROWS2

  k_gru <<<NODES/16, 512, 0, stream>>>(X, gW, gU, gb, pW, pb, sattW,
                                       node, actb, sng2);
  k_attn<<<NODES/4, 256, 0, stream>>>(node, nbrs, sattW, sattb, rattW, rattb,
                                      predW, predb, relemb, actb, sng2, out);
}